// Round 6
// baseline (4327.094 us; speedup 1.0000x reference)
//
#include <hip/hip_runtime.h>
#include <cstdint>
#include <cstddef>

typedef __attribute__((ext_vector_type(8))) short s16x8;
typedef __attribute__((ext_vector_type(4))) float f32x4;
typedef unsigned long long u64;

#define HID 1024
#define BATCH 32
#define SEQ 512
#define NWG 64

__device__ __forceinline__ short f2bf(float f){
  unsigned u = __builtin_bit_cast(unsigned, f);
  u = (u + 0x7fffu + ((u >> 16) & 1u)) >> 16;
  return (short)u;
}
__device__ __forceinline__ float bf2f(short s){
  unsigned u = ((unsigned)(unsigned short)s) << 16;
  return __builtin_bit_cast(float, u);
}

union U128 { struct { u64 lo, hi; } q; s16x8 v; };

// ---------------- pack x into A-fragment tiles (for gemm_xp) ----------------
__global__ __launch_bounds__(256) void pack_x_kernel(const float* __restrict__ x,
                                                     s16x8* __restrict__ xpk){
  int P = blockIdx.x * 256 + threadIdx.x;      // 2,097,152 total
  int lane = P & 63;
  int w = (P >> 6) & 15; int ks = w >> 3, mt = w & 7;
  int tile = P >> 10; int kt = tile & 15; int mb = tile >> 4;
  int row = mb * 128 + mt * 16 + (lane & 15);
  int k0 = kt * 64 + ks * 32 + (lane >> 4) * 8;
  const f32x4* src = (const f32x4*)(x + (size_t)row * HID + k0);
  f32x4 v0 = src[0], v1 = src[1];
  s16x8 o;
  o[0]=f2bf(v0[0]); o[1]=f2bf(v0[1]); o[2]=f2bf(v0[2]); o[3]=f2bf(v0[3]);
  o[4]=f2bf(v1[0]); o[5]=f2bf(v1[1]); o[6]=f2bf(v1[2]); o[7]=f2bf(v1[3]);
  xpk[P] = o;
}

// ---------------- pack input weights (4 gates side by side, N=4096) ----------------
__global__ __launch_bounds__(256) void pack_wx_kernel(const float* __restrict__ Wii,
    const float* __restrict__ Wif, const float* __restrict__ Wig,
    const float* __restrict__ Wio, s16x8* __restrict__ wxpk){
  int P = blockIdx.x * 256 + threadIdx.x;      // 524,288 total
  int lane = P & 63;
  int w = (P >> 6) & 15; int ks = w >> 3, nt = w & 7;
  int tile = P >> 10; int kt = tile & 15; int nb = tile >> 4;
  int n = nb * 128 + nt * 16 + (lane & 15);
  int g = n >> 10, c = n & 1023;
  int k0 = kt * 64 + ks * 32 + (lane >> 4) * 8;
  const float* W = (g == 0) ? Wii : (g == 1) ? Wif : (g == 2) ? Wig : Wio;
  s16x8 o;
  #pragma unroll
  for (int j = 0; j < 8; ++j) o[j] = f2bf(W[(size_t)(k0 + j) * HID + c]);
  wxpk[P] = o;
}

// ---------------- pack W_h^T into A-fragment tiles, gate-interleaved ----------------
// whpk: [wg(64)][q(32)][mt(4)][lane(64)] 16B units. Packed M index m = mt*16 + (lane&15):
// gate g = m&3, hcol = wg*16 + (m>>2). k = q*32 + (lane>>4)*8 + j.
// After mfma(Wt,h): lane's 4 regs = the 4 gates of (b=lane&15 of nt-half, hcol=wgbase+mt*4+(lane>>4)).
__global__ __launch_bounds__(256) void pack_wh_kernel(const float* __restrict__ Whi,
    const float* __restrict__ Whf, const float* __restrict__ Whg,
    const float* __restrict__ Who, s16x8* __restrict__ whpk){
  int P = blockIdx.x * 256 + threadIdx.x;      // 524,288 total
  int lane = P & 63;
  int mt = (P >> 6) & 3;
  int q  = (P >> 8) & 31;
  int wg = P >> 13;
  int m16 = lane & 15;
  int g = m16 & 3;
  int c = wg * 16 + mt * 4 + (m16 >> 2);
  int k0 = q * 32 + (lane >> 4) * 8;
  const float* W = (g == 0) ? Whi : (g == 1) ? Whf : (g == 2) ? Whg : Who;
  s16x8 o;
  #pragma unroll
  for (int j = 0; j < 8; ++j) o[j] = f2bf(W[(size_t)(k0 + j) * HID + c]);
  whpk[P] = o;
}

// ---------------- init: bias sums, h0 -> hseq slot 0, flags reset ----------------
__global__ __launch_bounds__(256) void init_kernel(const float* __restrict__ h0,
    const float* bii, const float* bif, const float* big, const float* bio,
    const float* bhi, const float* bhf, const float* bhg, const float* bho,
    float* __restrict__ bias_sum, u64* __restrict__ hseq, int* __restrict__ flags){
  int T = blockIdx.x * 256 + threadIdx.x;
  if (T < 4096){
    int g = T >> 10, c = T & 1023;
    const float* bi = (g == 0) ? bii : (g == 1) ? bif : (g == 2) ? big : bio;
    const float* bh = (g == 0) ? bhi : (g == 1) ? bhf : (g == 2) ? bhg : bho;
    bias_sum[T] = bi[c] + bh[c];
  } else if (T < 8192){
    int u = T - 4096;                 // 4096 units of 8 bf16 -> hseq slot 0
    int lane = u & 63; int q = u >> 6;
    int kstep = q & 31; int mtb = q >> 5;
    int b = mtb * 16 + (lane & 15);
    int col0 = kstep * 32 + (lane >> 4) * 8;
    const float* src = h0 + (size_t)b * HID + col0;
    s16x8 o;
    #pragma unroll
    for (int j = 0; j < 8; ++j) o[j] = f2bf(src[j]);
    u64 lo = (u64)(unsigned short)o[0] | ((u64)(unsigned short)o[1]<<16)
           | ((u64)(unsigned short)o[2]<<32) | ((u64)(unsigned short)o[3]<<48);
    u64 hi = (u64)(unsigned short)o[4] | ((u64)(unsigned short)o[5]<<16)
           | ((u64)(unsigned short)o[6]<<32) | ((u64)(unsigned short)o[7]<<48);
    __hip_atomic_store(hseq + 2*u,     lo, __ATOMIC_RELAXED, __HIP_MEMORY_SCOPE_AGENT);
    __hip_atomic_store(hseq + 2*u + 1, hi, __ATOMIC_RELAXED, __HIP_MEMORY_SCOPE_AGENT);
  } else if (T < 8192 + 65536){
    flags[T - 8192] = 0;              // 512 rows x 256 u16 flags, re-zero every launch
  }
}

// ---------------- phase 1: XP = x @ [Wii|Wif|Wig|Wio] + (b_i + b_h) ----------------
// Output: XP[t][c][b][g] bf16 (u64 per (b,c), coalesced across b in recurrence).
__global__ __launch_bounds__(256) void gemm_xp_kernel(const s16x8* __restrict__ xpk,
    const s16x8* __restrict__ wxpk, const float* __restrict__ bias_sum,
    short* __restrict__ XP){
  const int mb = blockIdx.x, nb = blockIdx.y;
  const int tid = threadIdx.x, lane = tid & 63, wave = tid >> 6;
  const int wr = wave >> 1, wc = wave & 1;
  __shared__ s16x8 sA[1024];   // 16KB
  __shared__ s16x8 sB[1024];   // 16KB
  f32x4 acc[4][4] = {};
  const s16x8* gA = xpk + (size_t)(mb * 16) * 1024;
  const s16x8* gB = wxpk + (size_t)(nb * 16) * 1024;
  for (int kt = 0; kt < 16; ++kt){
    __syncthreads();
    #pragma unroll
    for (int i = 0; i < 4; ++i){
      sA[i * 256 + tid] = gA[(size_t)kt * 1024 + i * 256 + tid];
      sB[i * 256 + tid] = gB[(size_t)kt * 1024 + i * 256 + tid];
    }
    __syncthreads();
    #pragma unroll
    for (int ks = 0; ks < 2; ++ks){
      s16x8 af[4], bfr[4];
      #pragma unroll
      for (int i = 0; i < 4; ++i) af[i] = sA[(ks * 8 + wr * 4 + i) * 64 + lane];
      #pragma unroll
      for (int j = 0; j < 4; ++j) bfr[j] = sB[(ks * 8 + wc * 4 + j) * 64 + lane];
      #pragma unroll
      for (int i = 0; i < 4; ++i)
        #pragma unroll
        for (int j = 0; j < 4; ++j)
          acc[i][j] = __builtin_amdgcn_mfma_f32_16x16x32_bf16(af[i], bfr[j], acc[i][j], 0, 0, 0);
    }
  }
  #pragma unroll
  for (int i = 0; i < 4; ++i){
    const int m_base = mb * 128 + (wr * 4 + i) * 16 + ((lane >> 4) << 2);
    #pragma unroll
    for (int j = 0; j < 4; ++j){
      const int n = nb * 128 + (wc * 4 + j) * 16 + (lane & 15);
      const float bias = bias_sum[n];
      const int g = n >> 10, c = n & 1023;
      #pragma unroll
      for (int r = 0; r < 4; ++r){
        const int m = m_base + r;
        const int tt = m & 511, bb = m >> 9;
        XP[(((size_t)tt * 1024 + c) * 32 + bb) * 4 + g] = f2bf(acc[i][j][r] + bias);
      }
    }
  }
}

// ---------------- phase 2: persistent recurrence; free-running waves ----------------
// 64 WGs x 4 waves. Wave (mp=wave>>1, nt=wave&1) owns (b in nt-half) x (8 hcols).
// No __syncthreads in loop. pre = mfma(W^T, h): 4 gates land in one lane's 4 regs.
// hseq: 4-slot rotating LLC buffer (sc1). Per-wave u16 flags; poll = 1 u64 load + __all.
__global__ __launch_bounds__(256, 1) void lstm_rec_kernel(const s16x8* __restrict__ whpk,
    u64* __restrict__ hseq, unsigned short* __restrict__ flags,
    const short* __restrict__ XP, const float* __restrict__ c0,
    float* __restrict__ out, float* __restrict__ htct)
{
  extern __shared__ char smem[];
  s16x8* sW = (s16x8*)smem;                    // 128KB: [q(32)][mt(4)][lane(64)]

  const int wg = blockIdx.x;
  const int tid = threadIdx.x, lane = tid & 63, wave = tid >> 6;
  const int mp = wave >> 1, nt = wave & 1;

  // stage this WG's W^T slice into LDS once (8192 units)
  {
    const s16x8* gW = whpk + (size_t)wg * 8192;
    #pragma unroll
    for (int i = 0; i < 32; ++i) sW[i * 256 + tid] = gW[i * 256 + tid];
  }

  const int l16 = lane & 15, lhi = lane >> 4;
  const int b = nt * 16 + l16;
  const int hc0 = wg * 16 + mp * 8 + lhi;      // m-tile mp*2
  const int hc1 = hc0 + 4;                     // m-tile mp*2+1
  float cst0 = c0[b * HID + hc0];
  float cst1 = c0[b * HID + hc1];

  // publish positions (u16 index within a 64KB slot)
  const int pub0 = (((nt * 32 + (hc0 >> 5)) * 64 + ((hc0 >> 3) & 3) * 16 + l16) << 3) + (hc0 & 7);
  const int pub1 = (((nt * 32 + (hc1 >> 5)) * 64 + ((hc1 >> 3) & 3) * 16 + l16) << 3) + (hc1 & 7);

  __syncthreads();   // sW ready (only barrier in the kernel)

  const u64* XPq = (const u64*)XP;
  u64 xq0 = XPq[(size_t)hc0 * 32 + b];
  u64 xq1 = XPq[(size_t)hc1 * 32 + b];

  const int a0base = mp * 2, a1base = mp * 2 + 1;

  for (int t = 0; t < SEQ; ++t){
    // ---- wait for this nt-half of h_t (skip t=0: init published it) ----
    if (t > 0){
      const u64* fp = (const u64*)(flags + (size_t)t * 256 + nt * 128) + (lane & 31);
      while (true){
        u64 v = __hip_atomic_load(fp, __ATOMIC_RELAXED, __HIP_MEMORY_SCOPE_AGENT);
        if (__all(v == 0x0001000100010001ull)) break;
        __builtin_amdgcn_s_sleep(1);
      }
    }
    const u64* hs = hseq + (size_t)(t & 3) * 8192;

    // ---- preload all 32 h B-fragments (coalesced 16B/lane, sc1) ----
    U128 hb[32];
    #pragma unroll
    for (int q = 0; q < 32; ++q){
      const int u = (nt * 32 + q) * 64 + lane;
      hb[q].q.lo = __hip_atomic_load(hs + 2 * u,     __ATOMIC_RELAXED, __HIP_MEMORY_SCOPE_AGENT);
      hb[q].q.hi = __hip_atomic_load(hs + 2 * u + 1, __ATOMIC_RELAXED, __HIP_MEMORY_SCOPE_AGENT);
    }

    // ---- pre^T = W^T @ h^T : 4 independent acc chains (2 m-tiles x 2 k-halves) ----
    f32x4 a00 = {0.f,0.f,0.f,0.f}, a01 = a00, a10 = a00, a11 = a00;
    #pragma unroll
    for (int q = 0; q < 32; q += 2){
      a00 = __builtin_amdgcn_mfma_f32_16x16x32_bf16(sW[(q * 4 + a0base) * 64 + lane],       hb[q].v,     a00, 0, 0, 0);
      a10 = __builtin_amdgcn_mfma_f32_16x16x32_bf16(sW[(q * 4 + a1base) * 64 + lane],       hb[q].v,     a10, 0, 0, 0);
      a01 = __builtin_amdgcn_mfma_f32_16x16x32_bf16(sW[((q + 1) * 4 + a0base) * 64 + lane], hb[q + 1].v, a01, 0, 0, 0);
      a11 = __builtin_amdgcn_mfma_f32_16x16x32_bf16(sW[((q + 1) * 4 + a1base) * 64 + lane], hb[q + 1].v, a11, 0, 0, 0);
    }
    f32x4 p0 = a00 + a01;
    f32x4 p1 = a10 + a11;

    // ---- gates: all in-lane (regs 0..3 = gates i,f,g,o) ----
    float pi0 = p0[0] + bf2f((short)(xq0 & 0xffff));
    float pf0 = p0[1] + bf2f((short)((xq0 >> 16) & 0xffff));
    float pg0 = p0[2] + bf2f((short)((xq0 >> 32) & 0xffff));
    float po0 = p0[3] + bf2f((short)(xq0 >> 48));
    float pi1 = p1[0] + bf2f((short)(xq1 & 0xffff));
    float pf1 = p1[1] + bf2f((short)((xq1 >> 16) & 0xffff));
    float pg1 = p1[2] + bf2f((short)((xq1 >> 32) & 0xffff));
    float po1 = p1[3] + bf2f((short)(xq1 >> 48));

    float ig0 = 1.f / (1.f + __expf(-pi0));
    float fg0 = 1.f / (1.f + __expf(-pf0));
    float gg0 = tanhf(pg0);
    float og0 = 1.f / (1.f + __expf(-po0));
    float ig1 = 1.f / (1.f + __expf(-pi1));
    float fg1 = 1.f / (1.f + __expf(-pf1));
    float gg1 = tanhf(pg1);
    float og1 = 1.f / (1.f + __expf(-po1));

    cst0 = fg0 * cst0 + ig0 * gg0;
    cst1 = fg1 * cst1 + ig1 * gg1;
    float h0v = og0 * tanhf(cst0);
    float h1v = og1 * tanhf(cst1);

    if (t == SEQ - 1){
      out[((size_t)b * SEQ + t) * HID + hc0] = h0v;
      out[((size_t)b * SEQ + t) * HID + hc1] = h1v;
      htct[b * HID + hc0] = h0v;
      htct[b * HID + hc1] = h1v;
      htct[32 * HID + b * HID + hc0] = cst0;
      htct[32 * HID + b * HID + hc1] = cst1;
      break;
    }

    // ---- publish h (2 x u16 sc1), drain only these, then per-wave flag ----
    unsigned short* hp = (unsigned short*)(hseq + (size_t)((t + 1) & 3) * 8192);
    __hip_atomic_store(hp + pub0, (unsigned short)f2bf(h0v), __ATOMIC_RELAXED, __HIP_MEMORY_SCOPE_AGENT);
    __hip_atomic_store(hp + pub1, (unsigned short)f2bf(h1v), __ATOMIC_RELAXED, __HIP_MEMORY_SCOPE_AGENT);
    asm volatile("s_waitcnt vmcnt(0)" ::: "memory");
    if (lane == 0)
      __hip_atomic_store(flags + (size_t)(t + 1) * 256 + nt * 128 + wg * 2 + mp,
                         (unsigned short)1, __ATOMIC_RELAXED, __HIP_MEMORY_SCOPE_AGENT);

    // ---- fire-and-forget out stores + next-step XP prefetch (overlap next poll) ----
    out[((size_t)b * SEQ + t) * HID + hc0] = h0v;
    out[((size_t)b * SEQ + t) * HID + hc1] = h1v;
    xq0 = XPq[((size_t)(t + 1) * 1024 + hc0) * 32 + b];
    xq1 = XPq[((size_t)(t + 1) * 1024 + hc1) * 32 + b];
  }
}

extern "C" void kernel_launch(void* const* d_in, const int* in_sizes, int n_in,
                              void* d_out, int out_size, void* d_ws, size_t ws_size,
                              hipStream_t stream){
  const float* x   = (const float*)d_in[0];
  const float* h0  = (const float*)d_in[1];
  const float* c0  = (const float*)d_in[2];
  const float* Wii = (const float*)d_in[3];
  const float* Wif = (const float*)d_in[4];
  const float* Wig = (const float*)d_in[5];
  const float* Wio = (const float*)d_in[6];
  const float* Whi = (const float*)d_in[7];
  const float* Whf = (const float*)d_in[8];
  const float* Whg = (const float*)d_in[9];
  const float* Who = (const float*)d_in[10];
  const float* bii = (const float*)d_in[11];
  const float* bif = (const float*)d_in[12];
  const float* big = (const float*)d_in[13];
  const float* bio = (const float*)d_in[14];
  const float* bhi = (const float*)d_in[15];
  const float* bhf = (const float*)d_in[16];
  const float* bhg = (const float*)d_in[17];
  const float* bho = (const float*)d_in[18];

  char* ws = (char*)d_ws;
  s16x8* xpk      = (s16x8*)(ws);                         // 32 MB
  s16x8* wxpk     = (s16x8*)(ws + 33554432ull);           //  8 MB
  s16x8* whpk     = (s16x8*)(ws + 41943040ull);           //  8 MB
  short* XP       = (short*)(ws + 50331648ull);           // 128 MB
  u64*   hseq     = (u64*)  (ws + 184549376ull);          // 4 x 64 KB rotating
  float* bias_sum = (float*)(ws + 184811520ull);          // 16 KB
  int*   flags    = (int*)  (ws + 184827904ull);          // 512 x 256 u16 = 256 KB

  float* out  = (float*)d_out;
  float* htct = out + (size_t)BATCH * SEQ * HID;

  pack_x_kernel<<<8192, 256, 0, stream>>>(x, xpk);
  pack_wx_kernel<<<2048, 256, 0, stream>>>(Wii, Wif, Wig, Wio, wxpk);
  pack_wh_kernel<<<2048, 256, 0, stream>>>(Whi, Whf, Whg, Who, whpk);
  init_kernel<<<288, 256, 0, stream>>>(h0, bii, bif, big, bio,
                                       bhi, bhf, bhg, bho, bias_sum, hseq, flags);
  gemm_xp_kernel<<<dim3(128, 32), 256, 0, stream>>>(xpk, wxpk, bias_sum, XP);

  void* args[] = {(void*)&whpk, (void*)&hseq, (void*)&flags, (void*)&XP,
                  (void*)&c0, (void*)&out, (void*)&htct};
  hipLaunchCooperativeKernel((const void*)lstm_rec_kernel, dim3(NWG), dim3(256),
                             args, 131072, stream);
}

// Round 8
// 3355.547 us; speedup vs baseline: 1.2895x; 1.2895x over previous
//
#include <hip/hip_runtime.h>
#include <cstdint>
#include <cstddef>

typedef __attribute__((ext_vector_type(8))) short s16x8;
typedef __attribute__((ext_vector_type(4))) float f32x4;
typedef unsigned long long u64;

#define HID 1024
#define BATCH 32
#define SEQ 512
#define NWG_REC 128
#define NWG_GEMM 112
#define NWG_TOT 240

__device__ __forceinline__ short f2bf(float f){
  unsigned u = __builtin_bit_cast(unsigned, f);
  u = (u + 0x7fffu + ((u >> 16) & 1u)) >> 16;
  return (short)u;
}
__device__ __forceinline__ float bf2f(short s){
  unsigned u = ((unsigned)(unsigned short)s) << 16;
  return __builtin_bit_cast(float, u);
}

union U128 { struct { u64 lo, hi; } q; s16x8 v; };

// ---------------- pack x into A-fragment tiles ----------------
__global__ __launch_bounds__(256) void pack_x_kernel(const float* __restrict__ x,
                                                     s16x8* __restrict__ xpk){
  int P = blockIdx.x * 256 + threadIdx.x;      // 2,097,152 total
  int lane = P & 63;
  int w = (P >> 6) & 15; int ks = w >> 3, mt = w & 7;
  int tile = P >> 10; int kt = tile & 15; int mb = tile >> 4;
  int row = mb * 128 + mt * 16 + (lane & 15);
  int k0 = kt * 64 + ks * 32 + (lane >> 4) * 8;
  const f32x4* src = (const f32x4*)(x + (size_t)row * HID + k0);
  f32x4 v0 = src[0], v1 = src[1];
  s16x8 o;
  o[0]=f2bf(v0[0]); o[1]=f2bf(v0[1]); o[2]=f2bf(v0[2]); o[3]=f2bf(v0[3]);
  o[4]=f2bf(v1[0]); o[5]=f2bf(v1[1]); o[6]=f2bf(v1[2]); o[7]=f2bf(v1[3]);
  xpk[P] = o;
}

// ---------------- pack input weights (4 gates side by side, N=4096) ----------------
__global__ __launch_bounds__(256) void pack_wx_kernel(const float* __restrict__ Wii,
    const float* __restrict__ Wif, const float* __restrict__ Wig,
    const float* __restrict__ Wio, s16x8* __restrict__ wxpk){
  int P = blockIdx.x * 256 + threadIdx.x;      // 524,288 total
  int lane = P & 63;
  int w = (P >> 6) & 15; int ks = w >> 3, nt = w & 7;
  int tile = P >> 10; int kt = tile & 15; int nb = tile >> 4;
  int n = nb * 128 + nt * 16 + (lane & 15);
  int g = n >> 10, c = n & 1023;
  int k0 = kt * 64 + ks * 32 + (lane >> 4) * 8;
  const float* W = (g == 0) ? Wii : (g == 1) ? Wif : (g == 2) ? Wig : Wio;
  s16x8 o;
  #pragma unroll
  for (int j = 0; j < 8; ++j) o[j] = f2bf(W[(size_t)(k0 + j) * HID + c]);
  wxpk[P] = o;
}

// ---------------- pack recurrent weights per rec workgroup (R4 layout) ----------------
__global__ __launch_bounds__(256) void pack_wh_kernel(const float* __restrict__ Whi,
    const float* __restrict__ Whf, const float* __restrict__ Whg,
    const float* __restrict__ Who, s16x8* __restrict__ whpk){
  int P = blockIdx.x * 256 + threadIdx.x;      // 524,288 total
  int lane = P & 63;
  int q = P >> 6;
  int nt = q & 1; int ks = (q >> 1) & 1; int kt = (q >> 2) & 15; int wg = q >> 6;
  int col16 = lane & 15;
  int g = nt * 2 + (col16 >> 3);
  int c = wg * 8 + (col16 & 7);
  int k0 = kt * 64 + ks * 32 + (lane >> 4) * 8;
  const float* W = (g == 0) ? Whi : (g == 1) ? Whf : (g == 2) ? Whg : Who;
  s16x8 o;
  #pragma unroll
  for (int j = 0; j < 8; ++j) o[j] = f2bf(W[(size_t)(k0 + j) * HID + c]);
  whpk[P] = o;
}

// ---------------- init: bias sums, h0 -> hseq slot 0, flag reset ----------------
__global__ __launch_bounds__(256) void init_kernel(const float* __restrict__ h0,
    const float* bii, const float* bif, const float* big, const float* bio,
    const float* bhi, const float* bhf, const float* bhg, const float* bho,
    float* __restrict__ bias_sum, u64* __restrict__ hseq,
    unsigned int* __restrict__ hflags32, unsigned int* __restrict__ XPflag){
  int T = blockIdx.x * 256 + threadIdx.x;
  if (T < 4096){
    int g = T >> 10, c = T & 1023;
    const float* bi = (g == 0) ? bii : (g == 1) ? bif : (g == 2) ? big : bio;
    const float* bh = (g == 0) ? bhi : (g == 1) ? bhf : (g == 2) ? bhg : bho;
    bias_sum[T] = bi[c] + bh[c];
  } else if (T < 8192){
    int u = T - 4096;                 // 4096 units of 8 bf16 -> hseq slot 0
    int lane = u & 63; int q = u >> 6;
    int kstep = q & 31; int mtb = q >> 5;
    int b = mtb * 16 + (lane & 15);
    int col0 = kstep * 32 + (lane >> 4) * 8;
    const float* src = h0 + (size_t)b * HID + col0;
    s16x8 o;
    #pragma unroll
    for (int j = 0; j < 8; ++j) o[j] = f2bf(src[j]);
    u64 lo = (u64)(unsigned short)o[0] | ((u64)(unsigned short)o[1]<<16)
           | ((u64)(unsigned short)o[2]<<32) | ((u64)(unsigned short)o[3]<<48);
    u64 hi = (u64)(unsigned short)o[4] | ((u64)(unsigned short)o[5]<<16)
           | ((u64)(unsigned short)o[6]<<32) | ((u64)(unsigned short)o[7]<<48);
    __hip_atomic_store(hseq + 2*u,     lo, __ATOMIC_RELAXED, __HIP_MEMORY_SCOPE_AGENT);
    __hip_atomic_store(hseq + 2*u + 1, hi, __ATOMIC_RELAXED, __HIP_MEMORY_SCOPE_AGENT);
  } else if (T < 8192 + 131072){
    hflags32[T - 8192] = 0;           // 512 x 512 u16 wave flags
  } else if (T < 8192 + 131072 + 128){
    XPflag[T - 8192 - 131072] = 0;    // 4 s-block counters (+ padding)
  }
}

// ---------------- fused cooperative kernel: recurrence + XP GEMM ----------------
__global__ __launch_bounds__(256, 1) void lstm_fused_kernel(
    const s16x8* __restrict__ whpk, const s16x8* __restrict__ xpk,
    const s16x8* __restrict__ wxpk, const float* __restrict__ bias_sum,
    u64* __restrict__ hseq, unsigned short* __restrict__ hflags,
    unsigned int* __restrict__ XPflag, short* __restrict__ XP,
    const float* __restrict__ c0, float* __restrict__ out, float* __restrict__ htct)
{
  extern __shared__ char smem[];
  const int bid = blockIdx.x;
  const int tid = threadIdx.x, lane = tid & 63, wave = tid >> 6;

  if (bid >= NWG_REC){
    // ================= GEMM producer path =================
    s16x8* sA = (s16x8*)smem;     // 16KB
    s16x8* sB = sA + 1024;        // 16KB
    const int wr = wave >> 1, wc = wave & 1;
    for (int tau = bid - NWG_REC; tau < 4096; tau += NWG_GEMM){
      const int mb_lin = tau >> 5;
      const int mb = ((mb_lin & 31) << 2) | (mb_lin >> 5);   // s-block-major order
      const int nb = tau & 31;
      f32x4 acc[4][4] = {};
      const s16x8* gA = xpk + (size_t)(mb * 16) * 1024;
      const s16x8* gB = wxpk + (size_t)(nb * 16) * 1024;
      for (int kt = 0; kt < 16; ++kt){
        __syncthreads();
        #pragma unroll
        for (int i = 0; i < 4; ++i){
          sA[i * 256 + tid] = gA[(size_t)kt * 1024 + i * 256 + tid];
          sB[i * 256 + tid] = gB[(size_t)kt * 1024 + i * 256 + tid];
        }
        __syncthreads();
        #pragma unroll
        for (int ks = 0; ks < 2; ++ks){
          s16x8 af[4], bfr[4];
          #pragma unroll
          for (int i = 0; i < 4; ++i) af[i] = sA[(ks * 8 + wr * 4 + i) * 64 + lane];
          #pragma unroll
          for (int j = 0; j < 4; ++j) bfr[j] = sB[(ks * 8 + wc * 4 + j) * 64 + lane];
          #pragma unroll
          for (int i = 0; i < 4; ++i)
            #pragma unroll
            for (int j = 0; j < 4; ++j)
              acc[i][j] = __builtin_amdgcn_mfma_f32_16x16x32_bf16(af[i], bfr[j], acc[i][j], 0, 0, 0);
        }
      }
      unsigned short* XPu = (unsigned short*)XP;
      #pragma unroll
      for (int i = 0; i < 4; ++i){
        const int m_base = mb * 128 + (wr * 4 + i) * 16 + ((lane >> 4) << 2);
        #pragma unroll
        for (int j = 0; j < 4; ++j){
          const int n = nb * 128 + (wc * 4 + j) * 16 + (lane & 15);
          const float bias = bias_sum[n];
          const int g = n >> 10, cxl = n & 1023;
          #pragma unroll
          for (int r = 0; r < 4; ++r){
            const int m = m_base + r;
            const int tt = m & 511, bb = m >> 9;
            unsigned short v = (unsigned short)f2bf(acc[i][j][r] + bias);
            __hip_atomic_store(XPu + ((((size_t)(tt * 32 + bb)) << 10) + cxl) * 4 + g,
                               v, __ATOMIC_RELAXED, __HIP_MEMORY_SCOPE_AGENT);
          }
        }
      }
      asm volatile("s_waitcnt vmcnt(0)" ::: "memory");
      __syncthreads();              // all threads drained their stores
      if (tid == 0)
        __hip_atomic_fetch_add(&XPflag[mb & 3], 1u, __ATOMIC_RELAXED, __HIP_MEMORY_SCOPE_AGENT);
    }
    return;
  }

  // ================= recurrence path (R4 structure, single-poller) =================
  s16x8* sW  = (s16x8*)smem;                   // 64KB
  float* pre = (float*)(smem + 65536);         // [32][33] padded

  const int wg = bid;
  const int mt = wave >> 1, nt = wave & 1;

  {
    const s16x8* gW = whpk + (size_t)wg * 4096;
    #pragma unroll
    for (int i = 0; i < 16; ++i) sW[i * 256 + tid] = gW[i * 256 + tid];
  }

  const int b = tid >> 3, cc = tid & 7;
  const int hcol = wg * 8 + cc;
  float c = c0[b * HID + hcol];

  const int prow = mt * 16 + ((lane >> 4) << 2);
  const int pcol = nt * 16 + (lane & 15);

  const int unit = ((b >> 4) * 32 + (wg >> 2)) * 64 + (wg & 3) * 16 + (b & 15);
  const size_t pubq = (size_t)unit * 2 + ((tid >> 2) & 1);
  const bool is_asm = ((tid & 3) == 0);

  // wait for XP s-block 0 fully published (all 32 batches), then prefetch t=0
  if (wave == 0){
    while (__hip_atomic_load(&XPflag[0], __ATOMIC_RELAXED, __HIP_MEMORY_SCOPE_AGENT) < 1024u)
      __builtin_amdgcn_s_sleep(16);
  }
  __syncthreads();   // sW staged + s-block 0 ready

  const u64* XPq = (const u64*)XP;
  u64 xq = __hip_atomic_load(XPq + ((((size_t)b) << 10) + hcol),
                             __ATOMIC_RELAXED, __HIP_MEMORY_SCOPE_AGENT);

  for (int t = 0; t < SEQ; ++t){
    if (wave == 0 && t > 0){
      const u64* fp = (const u64*)(hflags + (size_t)t * 512);
      while (true){
        u64 v0 = __hip_atomic_load(fp + lane,      __ATOMIC_RELAXED, __HIP_MEMORY_SCOPE_AGENT);
        u64 v1 = __hip_atomic_load(fp + 64 + lane, __ATOMIC_RELAXED, __HIP_MEMORY_SCOPE_AGENT);
        if (__all((v0 == 0x0001000100010001ull) && (v1 == 0x0001000100010001ull))) break;
        __builtin_amdgcn_s_sleep(2);
      }
    }
    __syncthreads();

    const u64* hs = hseq + (size_t)(t & 3) * 8192;

    f32x4 a0 = {0.f,0.f,0.f,0.f}, a1 = a0, a2 = a0, a3 = a0;
    #pragma unroll
    for (int kk = 0; kk < 8; ++kk){
      U128 h0f, h1f, h2f, h3f;
      { int u = (mt * 32 + 0 * 8 + kk) * 64 + lane;
        h0f.q.lo = __hip_atomic_load(hs + 2*u,   __ATOMIC_RELAXED, __HIP_MEMORY_SCOPE_AGENT);
        h0f.q.hi = __hip_atomic_load(hs + 2*u+1, __ATOMIC_RELAXED, __HIP_MEMORY_SCOPE_AGENT); }
      { int u = (mt * 32 + 1 * 8 + kk) * 64 + lane;
        h1f.q.lo = __hip_atomic_load(hs + 2*u,   __ATOMIC_RELAXED, __HIP_MEMORY_SCOPE_AGENT);
        h1f.q.hi = __hip_atomic_load(hs + 2*u+1, __ATOMIC_RELAXED, __HIP_MEMORY_SCOPE_AGENT); }
      { int u = (mt * 32 + 2 * 8 + kk) * 64 + lane;
        h2f.q.lo = __hip_atomic_load(hs + 2*u,   __ATOMIC_RELAXED, __HIP_MEMORY_SCOPE_AGENT);
        h2f.q.hi = __hip_atomic_load(hs + 2*u+1, __ATOMIC_RELAXED, __HIP_MEMORY_SCOPE_AGENT); }
      { int u = (mt * 32 + 3 * 8 + kk) * 64 + lane;
        h3f.q.lo = __hip_atomic_load(hs + 2*u,   __ATOMIC_RELAXED, __HIP_MEMORY_SCOPE_AGENT);
        h3f.q.hi = __hip_atomic_load(hs + 2*u+1, __ATOMIC_RELAXED, __HIP_MEMORY_SCOPE_AGENT); }
      a0 = __builtin_amdgcn_mfma_f32_16x16x32_bf16(h0f.v, sW[((0*8+kk)*2+nt)*64+lane], a0, 0, 0, 0);
      a1 = __builtin_amdgcn_mfma_f32_16x16x32_bf16(h1f.v, sW[((1*8+kk)*2+nt)*64+lane], a1, 0, 0, 0);
      a2 = __builtin_amdgcn_mfma_f32_16x16x32_bf16(h2f.v, sW[((2*8+kk)*2+nt)*64+lane], a2, 0, 0, 0);
      a3 = __builtin_amdgcn_mfma_f32_16x16x32_bf16(h3f.v, sW[((3*8+kk)*2+nt)*64+lane], a3, 0, 0, 0);
    }
    f32x4 acc = (a0 + a1) + (a2 + a3);

    pre[(prow + 0) * 33 + pcol] = acc[0];
    pre[(prow + 1) * 33 + pcol] = acc[1];
    pre[(prow + 2) * 33 + pcol] = acc[2];
    pre[(prow + 3) * 33 + pcol] = acc[3];
    __syncthreads();

    float p0 = pre[b * 33 + 0 * 8 + cc] + bf2f((short)(xq & 0xffff));
    float p1 = pre[b * 33 + 1 * 8 + cc] + bf2f((short)((xq >> 16) & 0xffff));
    float p2 = pre[b * 33 + 2 * 8 + cc] + bf2f((short)((xq >> 32) & 0xffff));
    float p3 = pre[b * 33 + 3 * 8 + cc] + bf2f((short)(xq >> 48));
    float ig = 1.f / (1.f + __expf(-p0));
    float fg = 1.f / (1.f + __expf(-p1));
    float gg = tanhf(p2);
    float og = 1.f / (1.f + __expf(-p3));
    c = fg * c + ig * gg;
    float h = og * tanhf(c);

    if (t == SEQ - 1){
      out[((size_t)b * SEQ + t) * HID + hcol] = h;
      htct[b * HID + hcol] = h;
      htct[32 * HID + b * HID + hcol] = c;
      break;
    }

    unsigned hu = (unsigned)(unsigned short)f2bf(h);
    unsigned g0 = __shfl(hu, (lane & 60) | 0);
    unsigned g1 = __shfl(hu, (lane & 60) | 1);
    unsigned g2 = __shfl(hu, (lane & 60) | 2);
    unsigned g3 = __shfl(hu, (lane & 60) | 3);
    if (is_asm){
      u64 val = (u64)g0 | ((u64)g1 << 16) | ((u64)g2 << 32) | ((u64)g3 << 48);
      __hip_atomic_store(hseq + (size_t)((t + 1) & 3) * 8192 + pubq, val,
                         __ATOMIC_RELAXED, __HIP_MEMORY_SCOPE_AGENT);
    }
    asm volatile("s_waitcnt vmcnt(0)" ::: "memory");
    if (lane == 0)
      __hip_atomic_store(&hflags[(size_t)(t + 1) * 512 + wg * 4 + wave],
                         (unsigned short)1, __ATOMIC_RELAXED, __HIP_MEMORY_SCOPE_AGENT);

    out[((size_t)b * SEQ + t) * HID + hcol] = h;
    const int tn = t + 1;
    if ((tn & 127) == 0){
      while (__hip_atomic_load(&XPflag[tn >> 7], __ATOMIC_RELAXED, __HIP_MEMORY_SCOPE_AGENT) < 1024u)
        __builtin_amdgcn_s_sleep(16);
    }
    xq = __hip_atomic_load(XPq + ((((size_t)tn * 32 + b) << 10) + hcol),
                           __ATOMIC_RELAXED, __HIP_MEMORY_SCOPE_AGENT);
  }
}

extern "C" void kernel_launch(void* const* d_in, const int* in_sizes, int n_in,
                              void* d_out, int out_size, void* d_ws, size_t ws_size,
                              hipStream_t stream){
  const float* x   = (const float*)d_in[0];
  const float* h0  = (const float*)d_in[1];
  const float* c0  = (const float*)d_in[2];
  const float* Wii = (const float*)d_in[3];
  const float* Wif = (const float*)d_in[4];
  const float* Wig = (const float*)d_in[5];
  const float* Wio = (const float*)d_in[6];
  const float* Whi = (const float*)d_in[7];
  const float* Whf = (const float*)d_in[8];
  const float* Whg = (const float*)d_in[9];
  const float* Who = (const float*)d_in[10];
  const float* bii = (const float*)d_in[11];
  const float* bif = (const float*)d_in[12];
  const float* big = (const float*)d_in[13];
  const float* bio = (const float*)d_in[14];
  const float* bhi = (const float*)d_in[15];
  const float* bhf = (const float*)d_in[16];
  const float* bhg = (const float*)d_in[17];
  const float* bho = (const float*)d_in[18];

  char* ws = (char*)d_ws;
  s16x8* xpk      = (s16x8*)(ws);                         // 32 MB
  s16x8* wxpk     = (s16x8*)(ws + 33554432ull);           //  8 MB
  s16x8* whpk     = (s16x8*)(ws + 41943040ull);           //  8 MB
  short* XP       = (short*)(ws + 50331648ull);           // 128 MB
  u64*   hseq     = (u64*)  (ws + 184549376ull);          // 4 x 64 KB rotating
  float* bias_sum = (float*)(ws + 184811520ull);          // 16 KB
  unsigned short* hflags = (unsigned short*)(ws + 184827904ull);  // 512x512 u16 = 512 KB
  unsigned int*   XPflag = (unsigned int*)  (ws + 185352192ull);  // 4 (+pad) u32

  float* out  = (float*)d_out;
  float* htct = out + (size_t)BATCH * SEQ * HID;

  pack_x_kernel<<<8192, 256, 0, stream>>>(x, xpk);
  pack_wx_kernel<<<2048, 256, 0, stream>>>(Wii, Wif, Wig, Wio, wxpk);
  pack_wh_kernel<<<2048, 256, 0, stream>>>(Whi, Whf, Whg, Who, whpk);
  init_kernel<<<545, 256, 0, stream>>>(h0, bii, bif, big, bio,
                                       bhi, bhf, bhg, bho, bias_sum, hseq,
                                       (unsigned int*)hflags, XPflag);

  void* args[] = {(void*)&whpk, (void*)&xpk, (void*)&wxpk, (void*)&bias_sum,
                  (void*)&hseq, (void*)&hflags, (void*)&XPflag, (void*)&XP,
                  (void*)&c0, (void*)&out, (void*)&htct};
  hipLaunchCooperativeKernel((const void*)lstm_fused_kernel, dim3(NWG_TOT), dim3(256),
                             args, 65536 + 4224, stream);
}